// Round 1
// 502.648 us; speedup vs baseline: 1.7448x; 1.7448x over previous
//
#include <hip/hip_runtime.h>
#include <cstdint>
#include <cstddef>

#define B_ 8
#define C_ 64
#define N_ 4096
#define O_ 64
#define ROWS_ (B_*N_)          // 32768
#define NSPLIT_ 4              // candidate splits per row in k_knn
#define BUFSTRIDE_ 17          // u64 stride: lane i -> bank 2i mod 32 (2-way, free)

typedef unsigned long long u64;
typedef unsigned int u32;
typedef unsigned short u16;
typedef __attribute__((ext_vector_type(8))) short bf16x8;   // 8 bf16 = 4 VGPR
typedef __attribute__((ext_vector_type(16))) float f32x16;  // MFMA 32x32 acc

#define MFMA32(A,Bv,Cv) __builtin_amdgcn_mfma_f32_32x32x16_bf16(A,Bv,Cv,0,0,0)

// ---- workspace layout (bytes), total 35,782,656 (== previous session peak) ----
// xf   [ROWS][64] f32 : 0           (8 MB)   alive: transpose -> aggr
// sq   [ROWS]     f32 : 8388608     (128 KB) alive: transpose -> knn
// kd   [ROWS][4][16] u32 : 8519680  (8 MB)   alive: knn -> merge
// ki   [ROWS][4][16] u16 : 16908288 (4 MB)   alive: knn -> merge
// pack [B][128][12][64][8] bf16 : 21102592 (12 MB) alive: pack -> knn
// knn  [ROWS][16] i32 : 33685504    (2 MB)   alive: merge -> aggr
// -- aliases (regions dead by the time these are written): --
// h    [ROWS][64] f32 : 8519680  (aliases kd)
// h1   [ROWS][64] f32 : 16908288 (aliases ki + pack head)
// bn   sums/params    : 25296896 (inside dead pack tail, after h1 end)
#define OFF_XF   0
#define OFF_SQ   8388608
#define OFF_KD   8519680
#define OFF_KI   16908288
#define OFF_PACK 21102592
#define OFF_IDX  33685504
#define OFF_H    8519680
#define OFF_H1   16908288
#define OFF_BN   25296896

__device__ __forceinline__ void insert16(u64 kv[16], u64 key) {
  if (key < kv[15]) {
#pragma unroll
    for (int j = 15; j > 0; --j) {
      u64 a = kv[j-1], b = kv[j];
      kv[j] = (key < a) ? a : ((key < b) ? key : b);
    }
    kv[0] = (key < kv[0]) ? key : kv[0];
  }
}

// ---------------- K0: zero BN accumulators ----------------
__global__ void k_zero(float* __restrict__ p, int n) {
  int i = blockIdx.x * 256 + threadIdx.x;
  if (i < n) p[i] = 0.f;
}

// ---------------- K1: transpose [B,C,N] -> xf[B,N,C], plus sq ----------------
__global__ __launch_bounds__(256) void k_transpose(const float* __restrict__ x,
                                                   float* __restrict__ xf,
                                                   float* __restrict__ sq) {
  __shared__ float lds[64 * 65];
  const int b  = blockIdx.x >> 6;          // 8 batches
  const int n0 = (blockIdx.x & 63) << 6;   // 64 n-tiles of 64
  const int tid = threadIdx.x;
  const float* xb = x + (size_t)b * C_ * N_;
  {
    const int nn = tid & 63;
    const int c0 = tid >> 6;
#pragma unroll
    for (int i = 0; i < 16; ++i) {
      int c = c0 + i * 4;
      lds[c * 65 + nn] = xb[(size_t)c * N_ + n0 + nn];   // coalesced over n
    }
  }
  __syncthreads();
  {
    const int cc  = tid & 63;
    const int nn0 = tid >> 6;
#pragma unroll
    for (int i = 0; i < 16; ++i) {
      int nn = nn0 + i * 4;
      xf[((size_t)(b * N_ + n0 + nn)) * 64 + cc] = lds[cc * 65 + nn]; // coalesced over c
    }
  }
  if (tid < 64) {
    float s = 0.f;
#pragma unroll
    for (int c = 0; c < 64; ++c) { float v = lds[c * 65 + tid]; s += v * v; }
    sq[b * N_ + n0 + tid] = s;
  }
}

// ---------------- K1b: split xf into hi/mid/lo bf16 planes, MFMA-fragment order ----
// pack[b][tile(128)][combo(12 = prec*4+slice)][lane(64)][j(8)] bf16
// value = xf[b][tile*32 + (lane&31)][slice*16 + (lane>>5)*8 + j]
// Same layout serves both A (candidates, row=lane&31) and B (queries, col=lane&31):
// identical (lane-group,j)->k maps on A and B make any hw k-permutation cancel.
__global__ __launch_bounds__(256) void k_pack(const float* __restrict__ xf,
                                              u16* __restrict__ pack) {
  const int bx = blockIdx.x;
  const int tile = bx & 127;
  const int b = bx >> 7;
  const int tid = threadIdx.x;
  const int lane = tid & 63;
  const int slice = tid >> 6;                 // 4 k-slices of 16
  const int row = tile * 32 + (lane & 31);
  const int kb = slice * 16 + (lane >> 5) * 8;
  const float* src = xf + ((size_t)(b * N_ + row)) * 64 + kb;
  float4 v0 = *(const float4*)src;
  float4 v1 = *(const float4*)(src + 4);
  float v[8] = {v0.x, v0.y, v0.z, v0.w, v1.x, v1.y, v1.z, v1.w};
  bf16x8 H, M, L;
#pragma unroll
  for (int j = 0; j < 8; ++j) {
    float f = v[j];
    u32 u = __float_as_uint(f);
    u32 rh = (u + 0x7FFFu + ((u >> 16) & 1u)) >> 16;   // RNE to bf16
    float bh = __uint_as_float(rh << 16);
    float f1 = f - bh;                                  // exact (Sterbenz)
    u = __float_as_uint(f1);
    u32 rm = (u + 0x7FFFu + ((u >> 16) & 1u)) >> 16;
    float bm = __uint_as_float(rm << 16);
    float f2 = f1 - bm;                                 // exact
    u = __float_as_uint(f2);
    u32 rl = (u + 0x7FFFu + ((u >> 16) & 1u)) >> 16;
    H[j] = (short)rh; M[j] = (short)rm; L[j] = (short)rl;
  }
  u16* base = pack + ((size_t)(b * 128 + tile) * 12) * 512 + lane * 8;
  *(bf16x8*)(base + (size_t)(0 + slice) * 512) = H;
  *(bf16x8*)(base + (size_t)(4 + slice) * 512) = M;
  *(bf16x8*)(base + (size_t)(8 + slice) * 512) = L;
}

// ---------------- K2: MFMA distance tiles + fused per-query top-16 ----------------
// grid: 8 b x 32 qblk x 4 split = 1024 blocks of 256 (4 waves; wave = one 32-query tile).
// D[m][n] = cand_m . query_n via 24 mfma_32x32x16_bf16 (3-way split, 6 terms x 4 slices).
// Selection key: d = sq_m - 2*dot  (sq_n constant per query -> same ordering).
// C/D layout [hw-verified]: col=lane&31 (query), row=(reg&3)+8*(reg>>2)+4*(lane>>5).
__global__ __launch_bounds__(256, 3) void k_knn(const u16* __restrict__ pack,
                                                const float* __restrict__ sq,
                                                u32* __restrict__ kd,
                                                u16* __restrict__ ki) {
  __shared__ u64 buf[256 * BUFSTRIDE_];      // per-lane candidate buffers / merge scratch
  const int bx = blockIdx.x;
  const int split = bx & 3;
  const int qb = (bx >> 2) & 31;
  const int b = bx >> 7;
  const int tid = threadIdx.x;
  const int lane = tid & 63;
  const int wid = tid >> 6;
  const int qt = qb * 4 + wid;               // query tile 0..127
  const int h = lane >> 5;
  const u16* pb = pack + (size_t)b * (128 * 12 * 512) + lane * 8;

  // 12 persistent query fragments (48 VGPRs)
  const u16* qp = pb + (size_t)qt * (12 * 512);
  bf16x8 qh0 = *(const bf16x8*)(qp + 0*512), qh1 = *(const bf16x8*)(qp + 1*512);
  bf16x8 qh2 = *(const bf16x8*)(qp + 2*512), qh3 = *(const bf16x8*)(qp + 3*512);
  bf16x8 qm0 = *(const bf16x8*)(qp + 4*512), qm1 = *(const bf16x8*)(qp + 5*512);
  bf16x8 qm2 = *(const bf16x8*)(qp + 6*512), qm3 = *(const bf16x8*)(qp + 7*512);
  bf16x8 ql0 = *(const bf16x8*)(qp + 8*512), ql1 = *(const bf16x8*)(qp + 9*512);
  bf16x8 ql2 = *(const bf16x8*)(qp + 10*512), ql3 = *(const bf16x8*)(qp + 11*512);

  u64 kv[16];
#pragma unroll
  for (int j = 0; j < 16; ++j) kv[j] = 0xFF8000000000FFFFull;  // flip(+INF) | idx 0xFFFF
  float threshF = __uint_as_float(0x7F800000u);                // +INF
  u64* mybuf = buf + tid * BUFSTRIDE_;
  const float* sqb = sq + b * N_;

  for (int ct = 0; ct < 32; ++ct) {
    const int mt = split * 32 + ct;
    const u16* ap = pb + (size_t)mt * (12 * 512);
    bf16x8 ah0 = *(const bf16x8*)(ap + 0*512), ah1 = *(const bf16x8*)(ap + 1*512);
    bf16x8 ah2 = *(const bf16x8*)(ap + 2*512), ah3 = *(const bf16x8*)(ap + 3*512);
    bf16x8 am0 = *(const bf16x8*)(ap + 4*512), am1 = *(const bf16x8*)(ap + 5*512);
    bf16x8 am2 = *(const bf16x8*)(ap + 6*512), am3 = *(const bf16x8*)(ap + 7*512);
    bf16x8 al0 = *(const bf16x8*)(ap + 8*512), al1 = *(const bf16x8*)(ap + 9*512);
    bf16x8 al2 = *(const bf16x8*)(ap + 10*512), al3 = *(const bf16x8*)(ap + 11*512);

    f32x16 acc0 = {0,0,0,0,0,0,0,0,0,0,0,0,0,0,0,0};
    f32x16 acc1 = {0,0,0,0,0,0,0,0,0,0,0,0,0,0,0,0};
    // small terms first per acc; slices 0,2 -> acc0, slices 1,3 -> acc1 (chain ILP)
    acc0 = MFMA32(ah0, ql0, acc0);  acc1 = MFMA32(ah1, ql1, acc1);
    acc0 = MFMA32(al0, qh0, acc0);  acc1 = MFMA32(al1, qh1, acc1);
    acc0 = MFMA32(am0, qm0, acc0);  acc1 = MFMA32(am1, qm1, acc1);
    acc0 = MFMA32(ah0, qm0, acc0);  acc1 = MFMA32(ah1, qm1, acc1);
    acc0 = MFMA32(am0, qh0, acc0);  acc1 = MFMA32(am1, qh1, acc1);
    acc0 = MFMA32(ah0, qh0, acc0);  acc1 = MFMA32(ah1, qh1, acc1);
    acc0 = MFMA32(ah2, ql2, acc0);  acc1 = MFMA32(ah3, ql3, acc1);
    acc0 = MFMA32(al2, qh2, acc0);  acc1 = MFMA32(al3, qh3, acc1);
    acc0 = MFMA32(am2, qm2, acc0);  acc1 = MFMA32(am3, qm3, acc1);
    acc0 = MFMA32(ah2, qm2, acc0);  acc1 = MFMA32(ah3, qm3, acc1);
    acc0 = MFMA32(am2, qh2, acc0);  acc1 = MFMA32(am3, qh3, acc1);
    acc0 = MFMA32(ah2, qh2, acc0);  acc1 = MFMA32(ah3, qh3, acc1);

    const int m0 = mt * 32;
    const float* sp = sqb + m0 + 4 * h;      // broadcast loads per half-wave
    float4 s0 = *(const float4*)(sp);
    float4 s1 = *(const float4*)(sp + 8);
    float4 s2 = *(const float4*)(sp + 16);
    float4 s3 = *(const float4*)(sp + 24);
    float sqv[16] = {s0.x, s0.y, s0.z, s0.w, s1.x, s1.y, s1.z, s1.w,
                     s2.x, s2.y, s2.z, s2.w, s3.x, s3.y, s3.z, s3.w};
    int cnt = 0;
#pragma unroll
    for (int r = 0; r < 16; ++r) {
      float d = fmaf(-2.f, acc0[r] + acc1[r], sqv[r]);
      if (d < threshF) {
        u32 u = __float_as_uint(d);
        u ^= ((int)u < 0) ? 0xFFFFFFFFu : 0x80000000u;   // orderable key
        mybuf[cnt++] = ((u64)u << 32) | (u32)(m0 + 4 * h + (r & 3) + 8 * (r >> 2));
      }
    }
    if (__any(cnt != 0)) {                   // batch-drain (rare after warmup)
      for (int i = 0; i < cnt; ++i) insert16(kv, mybuf[i]);
      u32 k15 = (u32)(kv[15] >> 32);
      u32 uu = (k15 & 0x80000000u) ? (k15 ^ 0x80000000u) : ~k15;
      threshF = __uint_as_float(uu);
    }
  }

  // merge the two half-wave partials of each query (lane <-> lane^32, same wave)
#pragma unroll
  for (int j = 0; j < 16; ++j) mybuf[j] = kv[j];
  const u64* pbuf = buf + (tid ^ 32) * BUFSTRIDE_;
  for (int j = 0; j < 16; ++j) insert16(kv, pbuf[j]);

  if (lane < 32) {
    const int row = b * N_ + qt * 32 + lane;
    u32* dp = kd + ((size_t)row * NSPLIT_ + split) * 16;
    u16* ip = ki + ((size_t)row * NSPLIT_ + split) * 16;
#pragma unroll
    for (int j = 0; j < 16; ++j) {
      dp[j] = (u32)(kv[j] >> 32);
      ip[j] = (u16)(kv[j] & 0xFFFFu);
    }
  }
}

// ---------------- K3: merge 4 partial top-16 -> final 16 indices ----------------
__global__ __launch_bounds__(256) void k_merge(const u32* __restrict__ kd,
                                               const u16* __restrict__ ki,
                                               int* __restrict__ knn) {
  int r = blockIdx.x * 256 + threadIdx.x;
  u64 kv[16];
#pragma unroll
  for (int j = 0; j < 16; ++j) kv[j] = ~0ULL;
  const u32* dp = kd + (size_t)r * (NSPLIT_ * 16);
  const u16* ip = ki + (size_t)r * (NSPLIT_ * 16);
  for (int i = 0; i < NSPLIT_ * 16; ++i) {
    u64 key = ((u64)dp[i] << 32) | ip[i];
    insert16(kv, key);
  }
#pragma unroll
  for (int j = 0; j < 16; ++j) knn[r * 16 + j] = (int)(kv[j] & 0xFFFFu);
}

// ---------------- K4: GIN aggregation: h = (1+eps)*xf + sum_k xf[idx] ----------------
__global__ __launch_bounds__(256) void k_aggr(const float* __restrict__ xf,
                                              const int* __restrict__ knn,
                                              const float* __restrict__ eps_gin,
                                              float* __restrict__ h) {
  const int tid = threadIdx.x;
  const int r = blockIdx.x * 4 + (tid >> 6);   // wave per row
  const int c = tid & 63;
  const int b = r >> 12;
  const float* xfb = xf + (size_t)b * N_ * 64;
  const float eps = eps_gin[0];
  float v = (1.f + eps) * xf[(size_t)r * 64 + c];
  const int* kn = knn + r * 16;
#pragma unroll
  for (int j = 0; j < 16; ++j) {
    int m = kn[j];                              // wave-uniform scalar load
    v += xfb[(size_t)m * 64 + c];               // coalesced 256B row read
  }
  h[(size_t)r * 64 + c] = v;
}

// ---------------- K5: h1 = h @ w1 + b1, plus BN partial sums ----------------
__global__ __launch_bounds__(256) void k_gemm1(const float* __restrict__ h,
                                               const float* __restrict__ w1,
                                               const float* __restrict__ b1,
                                               float* __restrict__ h1,
                                               float* __restrict__ bn_acc) {
  __shared__ float w[64 * 64];
  __shared__ float rs[4][64], rs2[4][64];
  const int tid = threadIdx.x;
#pragma unroll
  for (int i = 0; i < 16; ++i) w[tid + i * 256] = w1[tid + i * 256];
  __syncthreads();
  const int o = tid & 63;
  const int q = tid >> 6;
  const int r0 = blockIdx.x * 64;
  const float bias = b1[o];
  float s = 0.f, s2 = 0.f;
#pragma unroll
  for (int i = 0; i < 16; ++i) {
    int row = r0 + q + i * 4;                   // wave-uniform row
    const float* hr = h + (size_t)row * 64;
    float acc = bias;
#pragma unroll
    for (int c = 0; c < 64; ++c) acc += hr[c] * w[c * 64 + o];
    h1[(size_t)row * 64 + o] = acc;
    s += acc; s2 += acc * acc;
  }
  rs[q][o] = s; rs2[q][o] = s2;
  __syncthreads();
  if (tid < 64) {
    float ts  = rs[0][tid] + rs[1][tid] + rs[2][tid] + rs[3][tid];
    float ts2 = rs2[0][tid] + rs2[1][tid] + rs2[2][tid] + rs2[3][tid];
    atomicAdd(&bn_acc[tid], ts);
    atomicAdd(&bn_acc[64 + tid], ts2);
  }
}

// ---------------- K6: finalize BN -> per-channel scale/shift ----------------
__global__ void k_bnfin(const float* __restrict__ bn_acc,
                        const float* __restrict__ gamma,
                        const float* __restrict__ beta,
                        float* __restrict__ bn_par) {
  int o = threadIdx.x;   // 64 threads
  const float inv = 1.f / (float)ROWS_;
  float mean = bn_acc[o] * inv;
  float var  = bn_acc[64 + o] * inv - mean * mean;
  float sc = gamma[o] * rsqrtf(var + 1e-5f);
  bn_par[o] = sc;
  bn_par[64 + o] = beta[o] - mean * sc;
}

// ---------------- K7: BN apply + GELU(erf) + GEMM2 + transposed store ----------------
__global__ __launch_bounds__(256) void k_final(const float* __restrict__ h1,
                                               const float* __restrict__ bn_par,
                                               const float* __restrict__ w2,
                                               const float* __restrict__ b2,
                                               float* __restrict__ out) {
  __shared__ float w[64 * 64];
  __shared__ float hg[64 * 65];                 // padded: kills stride-64 conflicts
  const int tid = threadIdx.x;
#pragma unroll
  for (int i = 0; i < 16; ++i) w[tid + i * 256] = w2[tid + i * 256];
  const int r0 = blockIdx.x * 64;
  const int b  = r0 >> 12;
  const int n0 = r0 & (N_ - 1);
  const int o = tid & 63;
  const int q = tid >> 6;
  const float sc = bn_par[o], sh = bn_par[64 + o];
#pragma unroll
  for (int i = 0; i < 16; ++i) {
    int rl = q + i * 4;
    float v = h1[(size_t)(r0 + rl) * 64 + o] * sc + sh;
    float g = 0.5f * v * (1.f + erff(v * 0.70710678118654752f));
    hg[rl * 65 + o] = g;
  }
  __syncthreads();
  const int nl = tid & 63;
#pragma unroll
  for (int i = 0; i < 16; ++i) {
    int o2 = q + i * 4;                         // wave-uniform
    float acc = b2[o2];
#pragma unroll
    for (int oo = 0; oo < 64; ++oo) acc += hg[nl * 65 + oo] * w[oo * 64 + o2];
    out[((size_t)(b * 64 + o2)) * N_ + n0 + nl] = acc;  // coalesced over n
  }
}

extern "C" void kernel_launch(void* const* d_in, const int* in_sizes, int n_in,
                              void* d_out, int out_size, void* d_ws, size_t ws_size,
                              hipStream_t stream) {
  const float* x     = (const float*)d_in[0];
  const float* w1    = (const float*)d_in[1];
  const float* b1    = (const float*)d_in[2];
  const float* gamma = (const float*)d_in[3];
  const float* beta  = (const float*)d_in[4];
  const float* w2    = (const float*)d_in[5];
  const float* b2    = (const float*)d_in[6];
  const float* eps_g = (const float*)d_in[7];
  float* out = (float*)d_out;

  char* ws = (char*)d_ws;
  float* xf   = (float*)(ws + OFF_XF);
  float* sq   = (float*)(ws + OFF_SQ);
  u32*   kd   = (u32*)  (ws + OFF_KD);
  u16*   ki   = (u16*)  (ws + OFF_KI);
  u16*   pack = (u16*)  (ws + OFF_PACK);
  int*   knn  = (int*)  (ws + OFF_IDX);
  float* h    = (float*)(ws + OFF_H);          // aliases kd (dead after merge)
  float* h1   = (float*)(ws + OFF_H1);         // aliases ki+pack head (dead after knn)
  float* bn_acc = (float*)(ws + OFF_BN);       // inside dead pack tail
  float* bn_par = (float*)(ws + OFF_BN + 512);

  k_transpose<<<512, 256, 0, stream>>>(x, xf, sq);
  k_pack<<<1024, 256, 0, stream>>>(xf, pack);
  k_knn<<<1024, 256, 0, stream>>>(pack, sq, kd, ki);
  k_merge<<<ROWS_ / 256, 256, 0, stream>>>(kd, ki, knn);
  k_zero<<<1, 256, 0, stream>>>(bn_acc, 128);   // after merge: bn region is dead pack
  k_aggr<<<ROWS_ / 4, 256, 0, stream>>>(xf, knn, eps_g, h);
  k_gemm1<<<ROWS_ / 64, 256, 0, stream>>>(h, w1, b1, h1, bn_acc);
  k_bnfin<<<1, 64, 0, stream>>>(bn_acc, gamma, beta, bn_par);
  k_final<<<ROWS_ / 64, 256, 0, stream>>>(h1, bn_par, w2, b2, out);
}

// Round 2
// 412.307 us; speedup vs baseline: 2.1271x; 1.2191x over previous
//
#include <hip/hip_runtime.h>
#include <cstdint>
#include <cstddef>

#define B_ 8
#define C_ 64
#define N_ 4096
#define O_ 64
#define ROWS_ (B_*N_)          // 32768
#define NSPLIT_ 2              // candidate splits per row in k_knn
#define BUFSTRIDE_ 29          // u64 per-lane buffer capacity (59.4 KB LDS)
#define DRAIN_AT_ 14           // drain when cnt>=14 -> post-tile max 13+16=29 fits

typedef unsigned long long u64;
typedef unsigned int u32;
typedef unsigned short u16;
typedef __attribute__((ext_vector_type(8))) short bf16x8;   // 8 bf16 = 4 VGPR
typedef __attribute__((ext_vector_type(16))) float f32x16;  // MFMA 32x32 acc

#define MFMA32(A,Bv,Cv) __builtin_amdgcn_mfma_f32_32x32x16_bf16(A,Bv,Cv,0,0,0)

// ---- workspace layout (bytes), total 31,588,352 ----
// xf   [ROWS][64] f32 : 0           (8 MB)   alive: transpose -> aggr
// sq   [ROWS]     f32 : 8388608     (128 KB) alive: transpose -> knn
// kd   [ROWS][2][16] u32 : 8519680  (4 MB)   alive: knn -> merge
// ki   [ROWS][2][16] u16 : 12713984 (2 MB)   alive: knn -> merge
// pack [B][128][12][64][8] bf16 : 16908288 (12 MB) alive: transpose -> knn
// knn  [ROWS][16] i32 : 29491200    (2 MB)   alive: merge -> aggr
// -- aliases (dead regions reused): --
// h    [ROWS][64] f32 : 8519680  (over kd+ki, dead after merge)
// h1   [ROWS][64] f32 : 16908288 (over pack head, dead after knn)
// bn   sums/params    : 25296896 (in pack tail, dead after knn)
#define OFF_XF   0
#define OFF_SQ   8388608
#define OFF_KD   8519680
#define OFF_KI   12713984
#define OFF_PACK 16908288
#define OFF_IDX  29491200
#define OFF_H    8519680
#define OFF_H1   16908288
#define OFF_BN   25296896

__device__ __forceinline__ void insert16(u64 kv[16], u64 key) {
  if (key < kv[15]) {
#pragma unroll
    for (int j = 15; j > 0; --j) {
      u64 a = kv[j-1], b = kv[j];
      kv[j] = (key < a) ? a : ((key < b) ? key : b);
    }
    kv[0] = (key < kv[0]) ? key : kv[0];
  }
}

// ---------------- K0: zero BN accumulators ----------------
__global__ void k_zero(float* __restrict__ p, int n) {
  int i = blockIdx.x * 256 + threadIdx.x;
  if (i < n) p[i] = 0.f;
}

// ---------------- K1: transpose [B,C,N] -> xf[B,N,C], sq, and bf16 split-pack ----
// pack[b][tile(128)][combo(12 = prec*4+slice)][lane(64)][j(8)] bf16
// value = xf[b][tile*32 + (lane&31)][slice*16 + (lane>>5)*8 + j]
__global__ __launch_bounds__(256) void k_transpose(const float* __restrict__ x,
                                                   float* __restrict__ xf,
                                                   float* __restrict__ sq,
                                                   u16* __restrict__ pack) {
  __shared__ float lds[64 * 65];
  const int b  = blockIdx.x >> 6;          // 8 batches
  const int n0 = (blockIdx.x & 63) << 6;   // 64 n-tiles of 64
  const int tid = threadIdx.x;
  const float* xb = x + (size_t)b * C_ * N_;
  {
    const int nn = tid & 63;
    const int c0 = tid >> 6;
#pragma unroll
    for (int i = 0; i < 16; ++i) {
      int c = c0 + i * 4;
      lds[c * 65 + nn] = xb[(size_t)c * N_ + n0 + nn];   // coalesced over n
    }
  }
  __syncthreads();
  {
    const int cc  = tid & 63;
    const int nn0 = tid >> 6;
#pragma unroll
    for (int i = 0; i < 16; ++i) {
      int nn = nn0 + i * 4;
      xf[((size_t)(b * N_ + n0 + nn)) * 64 + cc] = lds[cc * 65 + nn]; // coalesced over c
    }
  }
  if (tid < 64) {
    float s = 0.f;
#pragma unroll
    for (int c = 0; c < 64; ++c) { float v = lds[c * 65 + tid]; s += v * v; }
    sq[b * N_ + n0 + tid] = s;
  }
  // fused pack: this block covers pack tiles 2*(blockIdx&63) + {0,1}
  {
    const int lane = tid & 63;
    const int slice = tid >> 6;                  // 4 k-slices of 16
    const int kb = slice * 16 + (lane >> 5) * 8;
#pragma unroll
    for (int tl = 0; tl < 2; ++tl) {
      const int nl = tl * 32 + (lane & 31);
      bf16x8 H, M, L;
#pragma unroll
      for (int j = 0; j < 8; ++j) {
        float f = lds[(kb + j) * 65 + nl];
        u32 u = __float_as_uint(f);
        u32 rh = (u + 0x7FFFu + ((u >> 16) & 1u)) >> 16;   // RNE to bf16
        float bh = __uint_as_float(rh << 16);
        float f1 = f - bh;                                  // exact (Sterbenz)
        u = __float_as_uint(f1);
        u32 rm = (u + 0x7FFFu + ((u >> 16) & 1u)) >> 16;
        float bm = __uint_as_float(rm << 16);
        float f2 = f1 - bm;                                 // exact
        u = __float_as_uint(f2);
        u32 rl = (u + 0x7FFFu + ((u >> 16) & 1u)) >> 16;
        H[j] = (short)rh; M[j] = (short)rm; L[j] = (short)rl;
      }
      const int tile = ((blockIdx.x & 63) << 1) + tl;
      u16* basep = pack + ((size_t)(b * 128 + tile) * 12) * 512 + lane * 8;
      *(bf16x8*)(basep + (size_t)(0 + slice) * 512) = H;
      *(bf16x8*)(basep + (size_t)(4 + slice) * 512) = M;
      *(bf16x8*)(basep + (size_t)(8 + slice) * 512) = L;
    }
  }
}

// ---------------- K2: MFMA distance tiles + fused per-query top-16 ----------------
// grid: 8 b x 32 qblk x 2 split = 512 blocks of 256 (4 waves; wave = one 32-query tile).
// Per split: 64 candidate tiles, double-buffered fragment prefetch.
// C/D layout [hw-verified]: col=lane&31 (query), row=(reg&3)+8*(reg>>2)+4*(lane>>5).
#define KNN_LOAD(P, mt) do { const u16* ap_ = pb + (size_t)(mt) * (12*512); \
  P##h0 = *(const bf16x8*)(ap_ + 0*512);  P##h1 = *(const bf16x8*)(ap_ + 1*512); \
  P##h2 = *(const bf16x8*)(ap_ + 2*512);  P##h3 = *(const bf16x8*)(ap_ + 3*512); \
  P##m0 = *(const bf16x8*)(ap_ + 4*512);  P##m1 = *(const bf16x8*)(ap_ + 5*512); \
  P##m2 = *(const bf16x8*)(ap_ + 6*512);  P##m3 = *(const bf16x8*)(ap_ + 7*512); \
  P##l0 = *(const bf16x8*)(ap_ + 8*512);  P##l1 = *(const bf16x8*)(ap_ + 9*512); \
  P##l2 = *(const bf16x8*)(ap_ +10*512);  P##l3 = *(const bf16x8*)(ap_ +11*512); } while(0)

#define KNN_MFMA(P) \
  acc0 = MFMA32(P##h0, ql0, acc0);  acc1 = MFMA32(P##h1, ql1, acc1); \
  acc0 = MFMA32(P##l0, qh0, acc0);  acc1 = MFMA32(P##l1, qh1, acc1); \
  acc0 = MFMA32(P##m0, qm0, acc0);  acc1 = MFMA32(P##m1, qm1, acc1); \
  acc0 = MFMA32(P##h0, qm0, acc0);  acc1 = MFMA32(P##h1, qm1, acc1); \
  acc0 = MFMA32(P##m0, qh0, acc0);  acc1 = MFMA32(P##m1, qh1, acc1); \
  acc0 = MFMA32(P##h0, qh0, acc0);  acc1 = MFMA32(P##h1, qh1, acc1); \
  acc0 = MFMA32(P##h2, ql2, acc0);  acc1 = MFMA32(P##h3, ql3, acc1); \
  acc0 = MFMA32(P##l2, qh2, acc0);  acc1 = MFMA32(P##l3, qh3, acc1); \
  acc0 = MFMA32(P##m2, qm2, acc0);  acc1 = MFMA32(P##m3, qm3, acc1); \
  acc0 = MFMA32(P##h2, qm2, acc0);  acc1 = MFMA32(P##h3, qm3, acc1); \
  acc0 = MFMA32(P##m2, qh2, acc0);  acc1 = MFMA32(P##m3, qh3, acc1); \
  acc0 = MFMA32(P##h2, qh2, acc0);  acc1 = MFMA32(P##h3, qh3, acc1);

#define KNN_SELECT(MT) do { \
  const int m0_ = (MT) * 32; \
  const float* sp_ = sqb + m0_ + 4 * h; \
  float4 s0_ = *(const float4*)(sp_); \
  float4 s1_ = *(const float4*)(sp_ + 8); \
  float4 s2_ = *(const float4*)(sp_ + 16); \
  float4 s3_ = *(const float4*)(sp_ + 24); \
  float sqv_[16] = {s0_.x, s0_.y, s0_.z, s0_.w, s1_.x, s1_.y, s1_.z, s1_.w, \
                    s2_.x, s2_.y, s2_.z, s2_.w, s3_.x, s3_.y, s3_.z, s3_.w}; \
_Pragma("unroll") \
  for (int r_ = 0; r_ < 16; ++r_) { \
    float d_ = fmaf(-2.f, acc0[r_] + acc1[r_], sqv_[r_]); \
    if (d_ < threshF) { \
      u32 u_ = __float_as_uint(d_); \
      u_ ^= ((int)u_ < 0) ? 0xFFFFFFFFu : 0x80000000u; \
      mybuf[cnt++] = ((u64)u_ << 32) | (u32)(m0_ + 4 * h + (r_ & 3) + 8 * (r_ >> 2)); \
    } \
  } \
  if (__any(cnt >= DRAIN_AT_)) { \
    for (int i_ = 0; i_ < cnt; ++i_) insert16(kv, mybuf[i_]); \
    cnt = 0; \
    u32 k15_ = (u32)(kv[15] >> 32); \
    u32 uu_ = (k15_ & 0x80000000u) ? (k15_ ^ 0x80000000u) : ~k15_; \
    threshF = __uint_as_float(uu_); \
  } \
} while(0)

__global__ __launch_bounds__(256, 2) void k_knn(const u16* __restrict__ pack,
                                                const float* __restrict__ sq,
                                                u32* __restrict__ kd,
                                                u16* __restrict__ ki) {
  __shared__ u64 buf[256 * BUFSTRIDE_];      // per-lane candidate buffers / merge scratch
  const int bx = blockIdx.x;
  const int split = bx & 1;
  const int qb = (bx >> 1) & 31;
  const int b = bx >> 6;
  const int tid = threadIdx.x;
  const int lane = tid & 63;
  const int wid = tid >> 6;
  const int qt = qb * 4 + wid;               // query tile 0..127
  const int h = lane >> 5;
  const u16* pb = pack + (size_t)b * (128 * 12 * 512) + lane * 8;

  // 12 persistent query fragments (48 VGPRs)
  const u16* qp = pb + (size_t)qt * (12 * 512);
  bf16x8 qh0 = *(const bf16x8*)(qp + 0*512), qh1 = *(const bf16x8*)(qp + 1*512);
  bf16x8 qh2 = *(const bf16x8*)(qp + 2*512), qh3 = *(const bf16x8*)(qp + 3*512);
  bf16x8 qm0 = *(const bf16x8*)(qp + 4*512), qm1 = *(const bf16x8*)(qp + 5*512);
  bf16x8 qm2 = *(const bf16x8*)(qp + 6*512), qm3 = *(const bf16x8*)(qp + 7*512);
  bf16x8 ql0 = *(const bf16x8*)(qp + 8*512), ql1 = *(const bf16x8*)(qp + 9*512);
  bf16x8 ql2 = *(const bf16x8*)(qp + 10*512), ql3 = *(const bf16x8*)(qp + 11*512);

  u64 kv[16];
#pragma unroll
  for (int j = 0; j < 16; ++j) kv[j] = 0xFF8000000000FFFFull;  // flip(+INF) | idx 0xFFFF
  float threshF = __uint_as_float(0x7F800000u);                // +INF
  int cnt = 0;
  u64* mybuf = buf + tid * BUFSTRIDE_;
  const float* sqb = sq + b * N_;
  const int mbase = split * 64;

  bf16x8 Ah0, Ah1, Ah2, Ah3, Am0, Am1, Am2, Am3, Al0, Al1, Al2, Al3;
  bf16x8 Bh0, Bh1, Bh2, Bh3, Bm0, Bm1, Bm2, Bm3, Bl0, Bl1, Bl2, Bl3;

  KNN_LOAD(A, mbase);
  for (int ct = 0; ct < 64; ct += 2) {
    KNN_LOAD(B, mbase + ct + 1);                    // prefetch: in flight under MFMA+select
    {
      f32x16 acc0 = {0,0,0,0,0,0,0,0,0,0,0,0,0,0,0,0};
      f32x16 acc1 = {0,0,0,0,0,0,0,0,0,0,0,0,0,0,0,0};
      KNN_MFMA(A)
      KNN_SELECT(mbase + ct);
    }
    KNN_LOAD(A, mbase + ((ct + 2) & 63));           // last iter: harmless reload of tile 0
    {
      f32x16 acc0 = {0,0,0,0,0,0,0,0,0,0,0,0,0,0,0,0};
      f32x16 acc1 = {0,0,0,0,0,0,0,0,0,0,0,0,0,0,0,0};
      KNN_MFMA(B)
      KNN_SELECT(mbase + ct + 1);
    }
  }
  for (int i = 0; i < cnt; ++i) insert16(kv, mybuf[i]);   // final drain

  // merge the two half-wave partials of each query (lane <-> lane^32, same wave)
#pragma unroll
  for (int j = 0; j < 16; ++j) mybuf[j] = kv[j];
  const u64* pbuf = buf + (tid ^ 32) * BUFSTRIDE_;
  for (int j = 0; j < 16; ++j) insert16(kv, pbuf[j]);

  if (lane < 32) {
    const int row = b * N_ + qt * 32 + lane;
    u32* dp = kd + ((size_t)row * NSPLIT_ + split) * 16;
    u16* ip = ki + ((size_t)row * NSPLIT_ + split) * 16;
#pragma unroll
    for (int j = 0; j < 16; ++j) {
      dp[j] = (u32)(kv[j] >> 32);
      ip[j] = (u16)(kv[j] & 0xFFFFu);
    }
  }
}

// ---------------- K3: merge 2 partial top-16 -> final 16 indices ----------------
__global__ __launch_bounds__(256) void k_merge(const u32* __restrict__ kd,
                                               const u16* __restrict__ ki,
                                               int* __restrict__ knn) {
  int r = blockIdx.x * 256 + threadIdx.x;
  u64 kv[16];
#pragma unroll
  for (int j = 0; j < 16; ++j) kv[j] = ~0ULL;
  const u32* dp = kd + (size_t)r * (NSPLIT_ * 16);
  const u16* ip = ki + (size_t)r * (NSPLIT_ * 16);
  for (int i = 0; i < NSPLIT_ * 16; ++i) {
    u64 key = ((u64)dp[i] << 32) | ip[i];
    insert16(kv, key);
  }
#pragma unroll
  for (int j = 0; j < 16; ++j) knn[r * 16 + j] = (int)(kv[j] & 0xFFFFu);
}

// ---------------- K4: GIN aggregation: h = (1+eps)*xf + sum_k xf[idx] ----------------
__global__ __launch_bounds__(256) void k_aggr(const float* __restrict__ xf,
                                              const int* __restrict__ knn,
                                              const float* __restrict__ eps_gin,
                                              float* __restrict__ h) {
  const int tid = threadIdx.x;
  const int r = blockIdx.x * 4 + (tid >> 6);   // wave per row
  const int c = tid & 63;
  const int b = r >> 12;
  const float* xfb = xf + (size_t)b * N_ * 64;
  const float eps = eps_gin[0];
  float v = (1.f + eps) * xf[(size_t)r * 64 + c];
  const int* kn = knn + r * 16;
#pragma unroll
  for (int j = 0; j < 16; ++j) {
    int m = kn[j];                              // wave-uniform scalar load
    v += xfb[(size_t)m * 64 + c];               // coalesced 256B row read
  }
  h[(size_t)r * 64 + c] = v;
}

// ---------------- K5: h1 = h @ w1 + b1, plus BN partial sums ----------------
__global__ __launch_bounds__(256) void k_gemm1(const float* __restrict__ h,
                                               const float* __restrict__ w1,
                                               const float* __restrict__ b1,
                                               float* __restrict__ h1,
                                               float* __restrict__ bn_acc) {
  __shared__ float w[64 * 64];
  __shared__ float rs[4][64], rs2[4][64];
  const int tid = threadIdx.x;
#pragma unroll
  for (int i = 0; i < 16; ++i) w[tid + i * 256] = w1[tid + i * 256];
  __syncthreads();
  const int o = tid & 63;
  const int q = tid >> 6;
  const int r0 = blockIdx.x * 64;
  const float bias = b1[o];
  float s = 0.f, s2 = 0.f;
#pragma unroll
  for (int i = 0; i < 16; ++i) {
    int row = r0 + q + i * 4;                   // wave-uniform row
    const float* hr = h + (size_t)row * 64;
    float acc = bias;
#pragma unroll
    for (int c = 0; c < 64; ++c) acc += hr[c] * w[c * 64 + o];
    h1[(size_t)row * 64 + o] = acc;
    s += acc; s2 += acc * acc;
  }
  rs[q][o] = s; rs2[q][o] = s2;
  __syncthreads();
  if (tid < 64) {
    float ts  = rs[0][tid] + rs[1][tid] + rs[2][tid] + rs[3][tid];
    float ts2 = rs2[0][tid] + rs2[1][tid] + rs2[2][tid] + rs2[3][tid];
    atomicAdd(&bn_acc[tid], ts);
    atomicAdd(&bn_acc[64 + tid], ts2);
  }
}

// ---------------- K6: finalize BN -> per-channel scale/shift ----------------
__global__ void k_bnfin(const float* __restrict__ bn_acc,
                        const float* __restrict__ gamma,
                        const float* __restrict__ beta,
                        float* __restrict__ bn_par) {
  int o = threadIdx.x;   // 64 threads
  const float inv = 1.f / (float)ROWS_;
  float mean = bn_acc[o] * inv;
  float var  = bn_acc[64 + o] * inv - mean * mean;
  float sc = gamma[o] * rsqrtf(var + 1e-5f);
  bn_par[o] = sc;
  bn_par[64 + o] = beta[o] - mean * sc;
}

// ---------------- K7: BN apply + GELU(erf) + GEMM2 + transposed store ----------------
__global__ __launch_bounds__(256) void k_final(const float* __restrict__ h1,
                                               const float* __restrict__ bn_par,
                                               const float* __restrict__ w2,
                                               const float* __restrict__ b2,
                                               float* __restrict__ out) {
  __shared__ float w[64 * 64];
  __shared__ float hg[64 * 65];                 // padded: kills stride-64 conflicts
  const int tid = threadIdx.x;
#pragma unroll
  for (int i = 0; i < 16; ++i) w[tid + i * 256] = w2[tid + i * 256];
  const int r0 = blockIdx.x * 64;
  const int b  = r0 >> 12;
  const int n0 = r0 & (N_ - 1);
  const int o = tid & 63;
  const int q = tid >> 6;
  const float sc = bn_par[o], sh = bn_par[64 + o];
#pragma unroll
  for (int i = 0; i < 16; ++i) {
    int rl = q + i * 4;
    float v = h1[(size_t)(r0 + rl) * 64 + o] * sc + sh;
    float g = 0.5f * v * (1.f + erff(v * 0.70710678118654752f));
    hg[rl * 65 + o] = g;
  }
  __syncthreads();
  const int nl = tid & 63;
#pragma unroll
  for (int i = 0; i < 16; ++i) {
    int o2 = q + i * 4;                         // wave-uniform
    float acc = b2[o2];
#pragma unroll
    for (int oo = 0; oo < 64; ++oo) acc += hg[nl * 65 + oo] * w[oo * 64 + o2];
    out[((size_t)(b * 64 + o2)) * N_ + n0 + nl] = acc;  // coalesced over n
  }
}

extern "C" void kernel_launch(void* const* d_in, const int* in_sizes, int n_in,
                              void* d_out, int out_size, void* d_ws, size_t ws_size,
                              hipStream_t stream) {
  const float* x     = (const float*)d_in[0];
  const float* w1    = (const float*)d_in[1];
  const float* b1    = (const float*)d_in[2];
  const float* gamma = (const float*)d_in[3];
  const float* beta  = (const float*)d_in[4];
  const float* w2    = (const float*)d_in[5];
  const float* b2    = (const float*)d_in[6];
  const float* eps_g = (const float*)d_in[7];
  float* out = (float*)d_out;

  char* ws = (char*)d_ws;
  float* xf   = (float*)(ws + OFF_XF);
  float* sq   = (float*)(ws + OFF_SQ);
  u32*   kd   = (u32*)  (ws + OFF_KD);
  u16*   ki   = (u16*)  (ws + OFF_KI);
  u16*   pack = (u16*)  (ws + OFF_PACK);
  int*   knn  = (int*)  (ws + OFF_IDX);
  float* h    = (float*)(ws + OFF_H);          // aliases kd+ki (dead after merge)
  float* h1   = (float*)(ws + OFF_H1);         // aliases pack head (dead after knn)
  float* bn_acc = (float*)(ws + OFF_BN);       // inside dead pack tail
  float* bn_par = (float*)(ws + OFF_BN + 512);

  k_transpose<<<512, 256, 0, stream>>>(x, xf, sq, pack);
  k_knn<<<512, 256, 0, stream>>>(pack, sq, kd, ki);
  k_merge<<<ROWS_ / 256, 256, 0, stream>>>(kd, ki, knn);
  k_zero<<<1, 256, 0, stream>>>(bn_acc, 128);   // bn region: dead pack tail
  k_aggr<<<ROWS_ / 4, 256, 0, stream>>>(xf, knn, eps_g, h);
  k_gemm1<<<ROWS_ / 64, 256, 0, stream>>>(h, w1, b1, h1, bn_acc);
  k_bnfin<<<1, 64, 0, stream>>>(bn_acc, gamma, beta, bn_par);
  k_final<<<ROWS_ / 64, 256, 0, stream>>>(h1, bn_par, w2, b2, out);
}